// Round 6
// baseline (386.235 us; speedup 1.0000x reference)
//
#include <hip/hip_runtime.h>
#include <hip/hip_bf16.h>

// Problem constants
#define B_LON 15      // NLON
#define NW    32      // TYPE_OF_WINDOWS
#define NTOK  144     // N_TOK
#define DIM   192
#define NH    6
#define HD    32
#define K3    576     // 3*DIM
#define MROWS (B_LON*NW*NTOK)   // 69120
#define NN    (NTOK*NTOK)       // 20736
#define TROWS 3312    // WINDOW: 2^2 * 6^2 * (2*12-1)
#define SCALE 0.17677669529663687f  // 32^-0.5

typedef __attribute__((ext_vector_type(8))) short bf16x8;
typedef __attribute__((ext_vector_type(8))) unsigned short u16x8;
typedef __attribute__((ext_vector_type(4))) float f32x4;

__device__ inline unsigned short f2bf(float f) {
  __bf16 h = (__bf16)f;
  return __builtin_bit_cast(unsigned short, h);
}
__device__ inline float bf2f(unsigned short u) {
  union { unsigned int i; float f; } c;
  c.i = ((unsigned int)u) << 16;
  return c.f;
}

// element-octet counts for the convert kernel
#define NX8 1658880   // 69120*192/8
#define NQ8 13824     // 576*192/8
#define NP8 4608      // 192*192/8

// ---------------------------------------------------------------------------
// Kernel -1: fp32 -> bf16 pre-convert of x, qkv_w, proj_w. (R4 version; the
// R5 fp32-X-in-kernel variant regressed fused by doubling phase-1 load bytes
// and adding in-loop converts.)
// ---------------------------------------------------------------------------
__global__ __launch_bounds__(256) void conv_bf_k(
    const float* __restrict__ x, const float* __restrict__ qw,
    const float* __restrict__ pw,
    unsigned short* __restrict__ xbf, unsigned short* __restrict__ qwbf,
    unsigned short* __restrict__ pwbf) {
  const long gid = (long)blockIdx.x * 256 + threadIdx.x;
  const float* src;
  unsigned short* dst;
  long off;
  if (gid < NX8)            { src = x;  dst = xbf;  off = gid; }
  else if (gid < NX8 + NQ8) { src = qw; dst = qwbf; off = gid - NX8; }
  else                      { src = pw; dst = pwbf; off = gid - NX8 - NQ8; }
  const float4 a = ((const float4*)src)[off * 2];
  const float4 b = ((const float4*)src)[off * 2 + 1];
  u16x8 u = {f2bf(a.x), f2bf(a.y), f2bf(a.z), f2bf(a.w),
             f2bf(b.x), f2bf(b.y), f2bf(b.z), f2bf(b.w)};
  *(u16x8*)&dst[off * 8] = u;
}

// ---------------------------------------------------------------------------
// Kernel 0: bias precompute v2 — LDS-staged column gather.
// Old version did 4M random 4B gathers from btab (stride-768B column walk,
// ~200cyc L2 each). Now block wh stages its 3312-float column into LDS once,
// then all 20736 gathers for that wh are LDS reads. Grid (192, 3).
// ---------------------------------------------------------------------------
__global__ __launch_bounds__(256) void bias_pre_k(
    const float* __restrict__ btab, const int* __restrict__ pos,
    unsigned short* __restrict__ biasb) {
  __shared__ float col[TROWS];
  const int wh = blockIdx.x;           // 0..191
  const int t  = threadIdx.x;
  for (int i = t; i < TROWS; i += 256)
    col[i] = btab[(size_t)i * (NW * NH) + wh];
  __syncthreads();
  unsigned short* dst = biasb + (size_t)wh * NN;
  const int seg = blockIdx.y * 6912;   // 3 segs of 6912 = 27*256
#pragma unroll
  for (int it = 0; it < 27; ++it) {
    const int e = seg + it * 256 + t;
    dst[e] = f2bf(col[pos[e]]);
  }
}

// ---------------------------------------------------------------------------
// Kernel 1+2 FUSED v7: 9-wave (576-thread) blocks.
// R4 diagnosis: latency-bound (MfmaUtil 8 / VALU 23 / HBM 10 / Occ 21 --
// nothing busy). Same dataflow as R4 (bf16 X, in-loop bias+mask), but each
// wave now owns ONE 16-row m-tile (phase 1) and ONE i-group (phase 2):
// per-wave serial chain is 3x shorter, and LDS 79.4 KB -> 2 blocks x 9
// waves = 18 waves/CU (vs 9). Still exactly one barrier.
// ---------------------------------------------------------------------------
__global__ __launch_bounds__(576, 5) void fused_attn_k(
    const unsigned short* __restrict__ X, const unsigned short* __restrict__ W,
    const float* __restrict__ Bv, const float* __restrict__ mask,
    const unsigned short* __restrict__ biasb, unsigned short* __restrict__ ao) {
  __shared__ unsigned short Qs[NTOK * 36];     // Q  [144][32] @ stride 36
  __shared__ unsigned short Ks[NTOK * 36];     // K  [144][32] @ stride 36
  __shared__ unsigned short Vs[32 * 160];      // V^T [32][144] @ stride 160, cols 144..159 zero
  __shared__ unsigned short Ps[9 * 16 * 168];  // per-wave P

  const int t    = threadIdx.x;
  const int wave = t / 64;                     // 0..8
  const int lane = t & 63;
  const int ln15 = lane & 15;
  const int quad = lane >> 4;
  const int idx  = blockIdx.x;
  const int xcd  = idx & 7;
  const int j0   = idx >> 3;
  const int h    = j0 % 6;
  const int bw   = (j0 / 6) * 8 + xcd;
  const int w    = bw & 31;
  const int wh   = w * NH + h;
  const float* maskp = mask + (size_t)bw * NN;
  const unsigned short* biasp = biasb + (size_t)wh * NN;
  unsigned short* ps = &Ps[wave * 16 * 168];

  // zero V pad cols 144..159
  if (t < 64) {
    u16x8 z = {0, 0, 0, 0, 0, 0, 0, 0};
    *(u16x8*)&Vs[(t >> 1) * 160 + 144 + (t & 1) * 8] = z;
  }
  // zero P pad cols 144..159 (per wave)
  {
    ushort4 z = {0, 0, 0, 0};
    *(ushort4*)&ps[(lane >> 2) * 168 + 144 + (lane & 3) * 4] = z;
  }

  // ---- phase 1: QKV GEMM; wave owns token rows [wave*16, wave*16+16) ----
  f32x4 acc[6];
#pragma unroll
  for (int nt = 0; nt < 6; ++nt) acc[nt] = (f32x4){0.f, 0.f, 0.f, 0.f};

#pragma unroll
  for (int kk = 0; kk < 6; ++kk) {
    const int k0 = kk * 32 + quad * 8;
    const bf16x8 af =
        *(const bf16x8*)&X[(size_t)(bw * NTOK + wave * 16 + ln15) * DIM + k0];
    bf16x8 bfr[6];
#pragma unroll
    for (int nt = 0; nt < 6; ++nt) {
      const int wrow = (nt >> 1) * DIM + h * HD + (nt & 1) * 16 + ln15;
      bfr[nt] = *(const bf16x8*)&W[(size_t)wrow * DIM + k0];
    }
#pragma unroll
    for (int nt = 0; nt < 6; ++nt)
      acc[nt] = __builtin_amdgcn_mfma_f32_16x16x32_bf16(af, bfr[nt], acc[nt], 0, 0, 0);
  }

  // epilogue: +bias (and scale for Q), straight into LDS
#pragma unroll
  for (int nt = 0; nt < 6; ++nt) {
    const int dd   = (nt & 1) * 16 + ln15;            // 0..31 within head
    const float bias = Bv[(nt >> 1) * DIM + h * HD + dd];
    const int tok = wave * 16 + quad * 4;
#pragma unroll
    for (int r = 0; r < 4; ++r) {
      const float v = acc[nt][r] + bias;
      if (nt < 2)      Qs[(tok + r) * 36 + dd] = f2bf(v * SCALE);
      else if (nt < 4) Ks[(tok + r) * 36 + dd] = f2bf(v);
      else             Vs[dd * 160 + tok + r]  = f2bf(v);
    }
  }
  __syncthreads();

  // ---- phase 2: attention; wave owns i-group g = wave ----
  {
    const int i0 = wave * 16;
    const int ib = i0 + quad * 4;

    // S = Q K^T
    const bf16x8 qf = *(const bf16x8*)&Qs[(i0 + ln15) * 36 + quad * 8];
    f32x4 s[9];
#pragma unroll
    for (int jt = 0; jt < 9; ++jt) {
      const bf16x8 kf = *(const bf16x8*)&Ks[(jt * 16 + ln15) * 36 + quad * 8];
      s[jt] = (f32x4){0.f, 0.f, 0.f, 0.f};
      s[jt] = __builtin_amdgcn_mfma_f32_16x16x32_bf16(qf, kf, s[jt], 0, 0, 0);
    }

    // + bias + mask (streamed, independent loads)
#pragma unroll
    for (int jt = 0; jt < 9; ++jt) {
      const int j = jt * 16 + ln15;
#pragma unroll
      for (int r = 0; r < 4; ++r) {
        const int ij = (ib + r) * NTOK + j;
        s[jt][r] += bf2f(biasp[ij]) + maskp[ij];
      }
    }

    // softmax over j (row = ib+r lives in the 16-lane ln15 group)
    float rinv[4];
#pragma unroll
    for (int r = 0; r < 4; ++r) {
      float mx = s[0][r];
#pragma unroll
      for (int jt = 1; jt < 9; ++jt) mx = fmaxf(mx, s[jt][r]);
#pragma unroll
      for (int off = 1; off < 16; off <<= 1) mx = fmaxf(mx, __shfl_xor(mx, off));
      float sum = 0.f;
#pragma unroll
      for (int jt = 0; jt < 9; ++jt) {
        const float e = __expf(s[jt][r] - mx);
        s[jt][r] = e;
        sum += e;
      }
#pragma unroll
      for (int off = 1; off < 16; off <<= 1) sum += __shfl_xor(sum, off);
      rinv[r] = 1.0f / sum;
    }

    // P: C-layout -> LDS -> A-layout (wave-internal)
#pragma unroll
    for (int jt = 0; jt < 9; ++jt)
#pragma unroll
      for (int r = 0; r < 4; ++r)
        ps[(quad * 4 + r) * 168 + jt * 16 + ln15] = f2bf(s[jt][r]);

    // O = P V  (K padded to 160; P and V pads both zeroed)
    f32x4 o[2] = {{0.f, 0.f, 0.f, 0.f}, {0.f, 0.f, 0.f, 0.f}};
#pragma unroll
    for (int kt = 0; kt < 5; ++kt) {
      const bf16x8 pf = *(const bf16x8*)&ps[ln15 * 168 + kt * 32 + quad * 8];
#pragma unroll
      for (int nt = 0; nt < 2; ++nt) {
        const bf16x8 vf = *(const bf16x8*)&Vs[(nt * 16 + ln15) * 160 + kt * 32 + quad * 8];
        o[nt] = __builtin_amdgcn_mfma_f32_16x16x32_bf16(pf, vf, o[nt], 0, 0, 0);
      }
    }

    // store O (bf16) into [m=bw*144+i][c=h*32+d]
#pragma unroll
    for (int nt = 0; nt < 2; ++nt)
#pragma unroll
      for (int r = 0; r < 4; ++r)
        ao[(size_t)(bw * NTOK + ib + r) * DIM + h * HD + nt * 16 + ln15] =
            f2bf(o[nt][r] * rinv[r]);
  }
}

// ---------------------------------------------------------------------------
// Kernel 3: proj GEMM v5 — LDS-free, direct-global fragments (the proven
// fused-phase-1 pattern). W (73 KB) is permanently L2-hot; AO rows are read
// exactly once, fully line-utilized (16 rows x 64B per fragment instr).
// No barrier, no staging; occupancy VGPR-bound (~4 blocks/CU, grid 1080).
// Wave w computes rows [m0+w*16, m0+w*16+16) x all 192 cols.
// ---------------------------------------------------------------------------
__global__ __launch_bounds__(256, 4) void proj_gemm_k(
    const unsigned short* __restrict__ AO, const unsigned short* __restrict__ W,
    const float* __restrict__ Bv, float* __restrict__ out) {
  const int t    = threadIdx.x;
  const int w    = t >> 6;
  const int lane = t & 63;
  const int ln15 = lane & 15;
  const int quad = lane >> 4;
  const int m0   = blockIdx.x * 64;
  const int mrow = m0 + w * 16 + ln15;

  f32x4 acc[12];
#pragma unroll
  for (int nt = 0; nt < 12; ++nt) acc[nt] = (f32x4){0.f, 0.f, 0.f, 0.f};

#pragma unroll
  for (int kk = 0; kk < 6; ++kk) {
    const int k0 = kk * 32 + quad * 8;
    const bf16x8 af = *(const bf16x8*)&AO[(size_t)mrow * DIM + k0];
    bf16x8 bfr[12];
#pragma unroll
    for (int nt = 0; nt < 12; ++nt)
      bfr[nt] = *(const bf16x8*)&W[(size_t)(nt * 16 + ln15) * DIM + k0];
#pragma unroll
    for (int nt = 0; nt < 12; ++nt)
      acc[nt] = __builtin_amdgcn_mfma_f32_16x16x32_bf16(af, bfr[nt], acc[nt], 0, 0, 0);
  }

#pragma unroll
  for (int nt = 0; nt < 12; ++nt) {
    const int colg = nt * 16 + ln15;
    const float bias = Bv[colg];
    const int mbase = m0 + w * 16 + quad * 4;
#pragma unroll
    for (int r = 0; r < 4; ++r)
      out[(size_t)(mbase + r) * DIM + colg] = acc[nt][r] + bias;
  }
}

// ---------------------------------------------------------------------------
extern "C" void kernel_launch(void* const* d_in, const int* in_sizes, int n_in,
                              void* d_out, int out_size, void* d_ws, size_t ws_size,
                              hipStream_t stream) {
  const float* x      = (const float*)d_in[0];
  const float* mask   = (const float*)d_in[1];
  const float* qkv_w  = (const float*)d_in[2];
  const float* qkv_b  = (const float*)d_in[3];
  const float* proj_w = (const float*)d_in[4];
  const float* proj_b = (const float*)d_in[5];
  const float* btab   = (const float*)d_in[6];
  const int*   pos    = (const int*)d_in[7];
  float* out = (float*)d_out;

  unsigned short* ws = (unsigned short*)d_ws;
  const size_t sz = (size_t)MROWS * DIM;   // 13,271,040 elements
  unsigned short* aobuf = ws;
  unsigned short* biasb = ws + sz + 256;                // 192*20736 bf16 = 8 MB
  unsigned short* xbf   = biasb + (size_t)192 * NN + 256;
  unsigned short* qwbf  = xbf + sz;
  unsigned short* pwbf  = qwbf + (size_t)K3 * DIM;

  conv_bf_k<<<NX8 / 256 + NQ8 / 256 + NP8 / 256, 256, 0, stream>>>(
      x, qkv_w, proj_w, xbf, qwbf, pwbf);
  bias_pre_k<<<dim3(NW * NH, 3), 256, 0, stream>>>(btab, pos, biasb);
  fused_attn_k<<<NH * 480, 576, 0, stream>>>(
      xbf, qwbf, qkv_b, mask, biasb, aobuf);
  proj_gemm_k<<<MROWS / 64, 256, 0, stream>>>(
      aobuf, pwbf, proj_b, out);
}

// Round 7
// 307.964 us; speedup vs baseline: 1.2542x; 1.2542x over previous
//
#include <hip/hip_runtime.h>
#include <hip/hip_bf16.h>

// Problem constants
#define B_LON 15      // NLON
#define NW    32      // TYPE_OF_WINDOWS
#define NTOK  144     // N_TOK
#define DIM   192
#define NH    6
#define HD    32
#define K3    576     // 3*DIM
#define MROWS (B_LON*NW*NTOK)   // 69120
#define NN    (NTOK*NTOK)       // 20736
#define TROWS 3312    // 2^2 * 6^2 * (2*12-1)
#define SCALE 0.17677669529663687f  // 32^-0.5

typedef __attribute__((ext_vector_type(8))) short bf16x8;
typedef __attribute__((ext_vector_type(8))) unsigned short u16x8;
typedef __attribute__((ext_vector_type(4))) float f32x4;

__device__ inline unsigned short f2bf(float f) {
  __bf16 h = (__bf16)f;
  return __builtin_bit_cast(unsigned short, h);
}
__device__ inline float bf2f(unsigned short u) {
  union { unsigned int i; float f; } c;
  c.i = ((unsigned int)u) << 16;
  return c.f;
}

// element-octet counts for the convert kernel
#define NX8 1658880   // 69120*192/8
#define NQ8 13824     // 576*192/8
#define NP8 4608      // 192*192/8

// ---------------------------------------------------------------------------
// Kernel -1: fp32 -> bf16 pre-convert of x, qkv_w, proj_w (R4 version).
// ---------------------------------------------------------------------------
__global__ __launch_bounds__(256) void conv_bf_k(
    const float* __restrict__ x, const float* __restrict__ qw,
    const float* __restrict__ pw,
    unsigned short* __restrict__ xbf, unsigned short* __restrict__ qwbf,
    unsigned short* __restrict__ pwbf) {
  const long gid = (long)blockIdx.x * 256 + threadIdx.x;
  const float* src;
  unsigned short* dst;
  long off;
  if (gid < NX8)            { src = x;  dst = xbf;  off = gid; }
  else if (gid < NX8 + NQ8) { src = qw; dst = qwbf; off = gid - NX8; }
  else                      { src = pw; dst = pwbf; off = gid - NX8 - NQ8; }
  const float4 a = ((const float4*)src)[off * 2];
  const float4 b = ((const float4*)src)[off * 2 + 1];
  u16x8 u = {f2bf(a.x), f2bf(a.y), f2bf(a.z), f2bf(a.w),
             f2bf(b.x), f2bf(b.y), f2bf(b.z), f2bf(b.w)};
  *(u16x8*)&dst[off * 8] = u;
}

// ---------------------------------------------------------------------------
// Kernel 0: bias precompute v2 — LDS-staged column gather (kept from R6:
// algorithmically dominant over the random-L2-gather v1).
// ---------------------------------------------------------------------------
__global__ __launch_bounds__(256) void bias_pre_k(
    const float* __restrict__ btab, const int* __restrict__ pos,
    unsigned short* __restrict__ biasb) {
  __shared__ float col[TROWS];
  const int wh = blockIdx.x;           // 0..191
  const int t  = threadIdx.x;
  for (int i = t; i < TROWS; i += 256)
    col[i] = btab[(size_t)i * (NW * NH) + wh];
  __syncthreads();
  unsigned short* dst = biasb + (size_t)wh * NN;
  const int seg = blockIdx.y * 6912;   // 3 segs of 6912 = 27*256
#pragma unroll
  for (int it = 0; it < 27; ++it) {
    const int e = seg + it * 256 + t;
    dst[e] = f2bf(col[pos[e]]);
  }
}

// ---------------------------------------------------------------------------
// Kernel 1+2 FUSED v8: R4 structure (192 thr / 3 waves / 47 KB LDS / one
// barrier) + SWAPPED QK^T.  R6 proved more-waves hurts (1 block/CU, VGPR 48);
// R4/R5 counters say issue/latency-bound on the per-g scalar tail:
// 72 scalar vmem loads + 32 shuffles + 36 scalar P-writes per lane per g.
// Computing S^T = mfma(K, Q) gives each lane a row-contiguous slice
// (i = ln15, j = jt*16+quad*4+r), so:
//   mask:   9 float4 loads   (was 36 scalar f32)
//   bias:   9 ushort4 loads  (was 36 scalar u16)
//   softmax: in-lane reduce over 36 + 2 shuffles + 1 rcp (was 32 shfl, 4 rcp)
//   P-write: 9 ushort4 (rinv folded in; was 36 scalar + rinv at O-store)
// PV and O-store structurally unchanged.
// ---------------------------------------------------------------------------
__global__ __launch_bounds__(192, 3) void fused_attn_k(
    const unsigned short* __restrict__ X, const unsigned short* __restrict__ W,
    const float* __restrict__ Bv, const float* __restrict__ mask,
    const unsigned short* __restrict__ biasb, unsigned short* __restrict__ ao) {
  __shared__ unsigned short Qs[NTOK * 36];     // Q  [144][32] @ stride 36
  __shared__ unsigned short Ks[NTOK * 36];     // K  [144][32] @ stride 36
  __shared__ unsigned short Vs[32 * 160];      // V^T [32][144] @ stride 160, cols 144..159 zero
  __shared__ unsigned short Ps[3 * 16 * 168];  // per-wave P [16 i][144+pad j]

  const int t    = threadIdx.x;
  const int wave = t / 64;
  const int lane = t & 63;
  const int ln15 = lane & 15;
  const int quad = lane >> 4;
  const int idx  = blockIdx.x;
  const int xcd  = idx & 7;
  const int j0   = idx >> 3;
  const int h    = j0 % 6;
  const int bw   = (j0 / 6) * 8 + xcd;
  const int w    = bw & 31;
  const int wh   = w * NH + h;
  const float* maskp = mask + (size_t)bw * NN;
  const unsigned short* biasp = biasb + (size_t)wh * NN;
  unsigned short* ps = &Ps[wave * 16 * 168];
  const int wv3 = wave * 3;

  // zero V pad cols 144..159
  if (t < 64) {
    u16x8 z = {0, 0, 0, 0, 0, 0, 0, 0};
    *(u16x8*)&Vs[(t >> 1) * 160 + 144 + (t & 1) * 8] = z;
  }
  // zero P pad cols 144..159 (per wave)
  {
    ushort4 z = {0, 0, 0, 0};
    *(ushort4*)&ps[(lane >> 2) * 168 + 144 + (lane & 3) * 4] = z;
  }

  // ---- phase 1: QKV GEMM for this (bw, h): 144 rows x 96 cols, K=192 ----
  f32x4 acc[3][6];
#pragma unroll
  for (int mt = 0; mt < 3; ++mt)
#pragma unroll
    for (int nt = 0; nt < 6; ++nt) acc[mt][nt] = (f32x4){0.f, 0.f, 0.f, 0.f};

#pragma unroll
  for (int kk = 0; kk < 6; ++kk) {
    const int k0 = kk * 32 + quad * 8;
    bf16x8 af[3], bfr[6];
#pragma unroll
    for (int mt = 0; mt < 3; ++mt)
      af[mt] = *(const bf16x8*)&X[(size_t)(bw * NTOK + (wv3 + mt) * 16 + ln15) * DIM + k0];
#pragma unroll
    for (int nt = 0; nt < 6; ++nt) {
      const int wrow = (nt >> 1) * DIM + h * HD + (nt & 1) * 16 + ln15;
      bfr[nt] = *(const bf16x8*)&W[(size_t)wrow * DIM + k0];
    }
#pragma unroll
    for (int mt = 0; mt < 3; ++mt)
#pragma unroll
      for (int nt = 0; nt < 6; ++nt)
        acc[mt][nt] = __builtin_amdgcn_mfma_f32_16x16x32_bf16(
            af[mt], bfr[nt], acc[mt][nt], 0, 0, 0);
  }

  // epilogue: +bias (and scale for Q), straight into LDS
#pragma unroll
  for (int nt = 0; nt < 6; ++nt) {
    const int dd   = (nt & 1) * 16 + ln15;            // 0..31 within head
    const float bias = Bv[(nt >> 1) * DIM + h * HD + dd];
#pragma unroll
    for (int mt = 0; mt < 3; ++mt) {
      const int tok = (wv3 + mt) * 16 + quad * 4;
#pragma unroll
      for (int r = 0; r < 4; ++r) {
        const float v = acc[mt][nt][r] + bias;
        if (nt < 2)      Qs[(tok + r) * 36 + dd] = f2bf(v * SCALE);
        else if (nt < 4) Ks[(tok + r) * 36 + dd] = f2bf(v);
        else             Vs[dd * 160 + tok + r]  = f2bf(v);
      }
    }
  }
  __syncthreads();

  // ---- phase 2: attention, swapped-operand QK^T ----
  for (int g = wv3; g < wv3 + 3; ++g) {
    const int i0 = g * 16;
    const int irow = i0 + ln15;          // this lane's q-row

    // S^T tiles: s[jt] rows j = jt*16+quad*4+r, cols i = i0+ln15
    const bf16x8 qf = *(const bf16x8*)&Qs[(i0 + ln15) * 36 + quad * 8];
    f32x4 s[9];
#pragma unroll
    for (int jt = 0; jt < 9; ++jt) {
      const bf16x8 kf = *(const bf16x8*)&Ks[(jt * 16 + ln15) * 36 + quad * 8];
      s[jt] = (f32x4){0.f, 0.f, 0.f, 0.f};
      s[jt] = __builtin_amdgcn_mfma_f32_16x16x32_bf16(kf, qf, s[jt], 0, 0, 0);
    }

    // + bias + mask: row-contiguous per lane -> vector loads
#pragma unroll
    for (int jt = 0; jt < 9; ++jt) {
      const int jb = jt * 16 + quad * 4;
      const float4  m4 = *(const float4*)&maskp[(size_t)irow * NTOK + jb];
      const ushort4 b4 = *(const ushort4*)&biasp[(size_t)irow * NTOK + jb];
      s[jt][0] += bf2f(b4.x) + m4.x;
      s[jt][1] += bf2f(b4.y) + m4.y;
      s[jt][2] += bf2f(b4.z) + m4.z;
      s[jt][3] += bf2f(b4.w) + m4.w;
    }

    // softmax over j: 36 in-lane values + 2 cross-quad shuffles
    float mx = s[0][0];
#pragma unroll
    for (int jt = 0; jt < 9; ++jt)
#pragma unroll
      for (int r = 0; r < 4; ++r) mx = fmaxf(mx, s[jt][r]);
    mx = fmaxf(mx, __shfl_xor(mx, 16));
    mx = fmaxf(mx, __shfl_xor(mx, 32));
    float sum = 0.f;
#pragma unroll
    for (int jt = 0; jt < 9; ++jt)
#pragma unroll
      for (int r = 0; r < 4; ++r) {
        const float e = __expf(s[jt][r] - mx);
        s[jt][r] = e;
        sum += e;
      }
    sum += __shfl_xor(sum, 16);
    sum += __shfl_xor(sum, 32);
    const float rinv = 1.0f / sum;

    // P write: normalized, vectorized (ushort4 per jt)
#pragma unroll
    for (int jt = 0; jt < 9; ++jt) {
      ushort4 pw = {f2bf(s[jt][0] * rinv), f2bf(s[jt][1] * rinv),
                    f2bf(s[jt][2] * rinv), f2bf(s[jt][3] * rinv)};
      *(ushort4*)&ps[ln15 * 168 + jt * 16 + quad * 4] = pw;
    }

    // O = P V  (K padded to 160; P and V pads both zeroed)
    f32x4 o[2] = {{0.f, 0.f, 0.f, 0.f}, {0.f, 0.f, 0.f, 0.f}};
#pragma unroll
    for (int kt = 0; kt < 5; ++kt) {
      const bf16x8 pf = *(const bf16x8*)&ps[ln15 * 168 + kt * 32 + quad * 8];
#pragma unroll
      for (int nt = 0; nt < 2; ++nt) {
        const bf16x8 vf = *(const bf16x8*)&Vs[(nt * 16 + ln15) * 160 + kt * 32 + quad * 8];
        o[nt] = __builtin_amdgcn_mfma_f32_16x16x32_bf16(pf, vf, o[nt], 0, 0, 0);
      }
    }

    // store O (bf16): row i = i0+quad*4+r, col d = h*32 + nt*16+ln15
    const int ib = i0 + quad * 4;
#pragma unroll
    for (int nt = 0; nt < 2; ++nt)
#pragma unroll
      for (int r = 0; r < 4; ++r)
        ao[(size_t)(bw * NTOK + ib + r) * DIM + h * HD + nt * 16 + ln15] =
            f2bf(o[nt][r]);
  }
}

// ---------------------------------------------------------------------------
// Kernel 3: proj GEMM v4 (R4 config) — M=128 x N=64 full-K single-barrier.
// ---------------------------------------------------------------------------
__global__ __launch_bounds__(256) void proj_gemm_k(
    const unsigned short* __restrict__ AO, const unsigned short* __restrict__ W,
    const float* __restrict__ Bv, float* __restrict__ out) {
  __shared__ unsigned short As[128 * 200];
  __shared__ unsigned short Bs[64 * 200];
  const int t    = threadIdx.x;
  const int n0   = blockIdx.x * 64;
  const int m0   = blockIdx.y * 128;
  const int w    = t >> 6;
  const int lane = t & 63;
  const int ln15 = lane & 15;
  const int quad = lane >> 4;

  // stage A: 128 rows x 24 u16x8 (contiguous region of AO)
#pragma unroll
  for (int it = t; it < 3072; it += 256) {
    const int row = it / 24;
    const int c8  = (it % 24) * 8;
    *(u16x8*)&As[row * 200 + c8] = *(const u16x8*)&AO[(size_t)(m0 + row) * 192 + c8];
  }
  // stage B: 64 rows of W (L2-hot)
#pragma unroll
  for (int it = t; it < 1536; it += 256) {
    const int row = it / 24;
    const int c8  = (it % 24) * 8;
    *(u16x8*)&Bs[row * 200 + c8] = *(const u16x8*)&W[(size_t)(n0 + row) * 192 + c8];
  }
  __syncthreads();

  f32x4 acc[2][4];
#pragma unroll
  for (int i = 0; i < 2; ++i)
#pragma unroll
    for (int jj = 0; jj < 4; ++jj) acc[i][jj] = (f32x4){0.f, 0.f, 0.f, 0.f};

#pragma unroll
  for (int k0 = 0; k0 < 192; k0 += 32) {
    bf16x8 af[2], bfr[4];
#pragma unroll
    for (int mt = 0; mt < 2; ++mt)
      af[mt] = *(bf16x8*)&As[(w * 32 + mt * 16 + ln15) * 200 + k0 + quad * 8];
#pragma unroll
    for (int nt = 0; nt < 4; ++nt)
      bfr[nt] = *(bf16x8*)&Bs[(nt * 16 + ln15) * 200 + k0 + quad * 8];
#pragma unroll
    for (int mt = 0; mt < 2; ++mt)
#pragma unroll
      for (int nt = 0; nt < 4; ++nt)
        acc[mt][nt] = __builtin_amdgcn_mfma_f32_16x16x32_bf16(
            af[mt], bfr[nt], acc[mt][nt], 0, 0, 0);
  }

#pragma unroll
  for (int nt = 0; nt < 4; ++nt) {
    const int colg = n0 + nt * 16 + ln15;
    const float bias = Bv[colg];
#pragma unroll
    for (int mt = 0; mt < 2; ++mt) {
#pragma unroll
      for (int r = 0; r < 4; ++r) {
        const int m = m0 + w * 32 + mt * 16 + quad * 4 + r;
        out[(size_t)m * 192 + colg] = acc[mt][nt][r] + bias;
      }
    }
  }
}

// ---------------------------------------------------------------------------
extern "C" void kernel_launch(void* const* d_in, const int* in_sizes, int n_in,
                              void* d_out, int out_size, void* d_ws, size_t ws_size,
                              hipStream_t stream) {
  const float* x      = (const float*)d_in[0];
  const float* mask   = (const float*)d_in[1];
  const float* qkv_w  = (const float*)d_in[2];
  const float* qkv_b  = (const float*)d_in[3];
  const float* proj_w = (const float*)d_in[4];
  const float* proj_b = (const float*)d_in[5];
  const float* btab   = (const float*)d_in[6];
  const int*   pos    = (const int*)d_in[7];
  float* out = (float*)d_out;

  unsigned short* ws = (unsigned short*)d_ws;
  const size_t sz = (size_t)MROWS * DIM;   // 13,271,040 elements
  unsigned short* aobuf = ws;
  unsigned short* biasb = ws + sz + 256;                // 192*20736 bf16 = 8 MB
  unsigned short* xbf   = biasb + (size_t)192 * NN + 256;
  unsigned short* qwbf  = xbf + sz;
  unsigned short* pwbf  = qwbf + (size_t)K3 * DIM;

  conv_bf_k<<<NX8 / 256 + NQ8 / 256 + NP8 / 256, 256, 0, stream>>>(
      x, qkv_w, proj_w, xbf, qwbf, pwbf);
  bias_pre_k<<<dim3(NW * NH, 3), 256, 0, stream>>>(btab, pos, biasb);
  fused_attn_k<<<NH * 480, 192, 0, stream>>>(
      xbf, qwbf, qkv_b, mask, biasb, aobuf);
  proj_gemm_k<<<dim3(DIM / 64, MROWS / 128), 256, 0, stream>>>(
      aobuf, pwbf, proj_b, out);
}

// Round 8
// 307.649 us; speedup vs baseline: 1.2554x; 1.0010x over previous
//
#include <hip/hip_runtime.h>
#include <hip/hip_bf16.h>

// Problem constants
#define B_LON 15      // NLON
#define NW    32      // TYPE_OF_WINDOWS
#define NTOK  144     // N_TOK
#define DIM   192
#define NH    6
#define HD    32
#define K3    576     // 3*DIM
#define MROWS (B_LON*NW*NTOK)   // 69120
#define NN    (NTOK*NTOK)       // 20736
#define TROWS 3312    // 2^2 * 6^2 * (2*12-1)
#define SCALE 0.17677669529663687f  // 32^-0.5

typedef __attribute__((ext_vector_type(8))) short bf16x8;
typedef __attribute__((ext_vector_type(8))) unsigned short u16x8;
typedef __attribute__((ext_vector_type(4))) float f32x4;

__device__ inline unsigned short f2bf(float f) {
  __bf16 h = (__bf16)f;
  return __builtin_bit_cast(unsigned short, h);
}
__device__ inline float bf2f(unsigned short u) {
  union { unsigned int i; float f; } c;
  c.i = ((unsigned int)u) << 16;
  return c.f;
}

// element-octet counts for the convert kernel
#define NX8 1658880   // 69120*192/8
#define NQ8 13824     // 576*192/8
#define NP8 4608      // 192*192/8

// ---------------------------------------------------------------------------
// Kernel -1: fp32 -> bf16 pre-convert of x, qkv_w, proj_w (R4 version).
// ---------------------------------------------------------------------------
__global__ __launch_bounds__(256) void conv_bf_k(
    const float* __restrict__ x, const float* __restrict__ qw,
    const float* __restrict__ pw,
    unsigned short* __restrict__ xbf, unsigned short* __restrict__ qwbf,
    unsigned short* __restrict__ pwbf) {
  const long gid = (long)blockIdx.x * 256 + threadIdx.x;
  const float* src;
  unsigned short* dst;
  long off;
  if (gid < NX8)            { src = x;  dst = xbf;  off = gid; }
  else if (gid < NX8 + NQ8) { src = qw; dst = qwbf; off = gid - NX8; }
  else                      { src = pw; dst = pwbf; off = gid - NX8 - NQ8; }
  const float4 a = ((const float4*)src)[off * 2];
  const float4 b = ((const float4*)src)[off * 2 + 1];
  u16x8 u = {f2bf(a.x), f2bf(a.y), f2bf(a.z), f2bf(a.w),
             f2bf(b.x), f2bf(b.y), f2bf(b.z), f2bf(b.w)};
  *(u16x8*)&dst[off * 8] = u;
}

// ---------------------------------------------------------------------------
// Kernel 0: bias precompute v2 — LDS-staged column gather.
// ---------------------------------------------------------------------------
__global__ __launch_bounds__(256) void bias_pre_k(
    const float* __restrict__ btab, const int* __restrict__ pos,
    unsigned short* __restrict__ biasb) {
  __shared__ float col[TROWS];
  const int wh = blockIdx.x;           // 0..191
  const int t  = threadIdx.x;
  for (int i = t; i < TROWS; i += 256)
    col[i] = btab[(size_t)i * (NW * NH) + wh];
  __syncthreads();
  unsigned short* dst = biasb + (size_t)wh * NN;
  const int seg = blockIdx.y * 6912;   // 3 segs of 6912 = 27*256
#pragma unroll
  for (int it = 0; it < 27; ++it) {
    const int e = seg + it * 256 + t;
    dst[e] = f2bf(col[pos[e]]);
  }
}

// ---------------------------------------------------------------------------
// Kernel 1+2 FUSED: exact R4 revert (114 us, FETCH 44 MB known-good).
// R7's swapped-QK^T variant cut issue count but destroyed mask/bias L2
// locality (FETCH 44->108 MB, WRITE 43->143 MB) -- access-pattern locality
// dominates issue count here.
// ---------------------------------------------------------------------------
__global__ __launch_bounds__(192, 3) void fused_attn_k(
    const unsigned short* __restrict__ X, const unsigned short* __restrict__ W,
    const float* __restrict__ Bv, const float* __restrict__ mask,
    const unsigned short* __restrict__ biasb, unsigned short* __restrict__ ao) {
  __shared__ unsigned short Qs[NTOK * 36];     // Q  [144][32] @ stride 36
  __shared__ unsigned short Ks[NTOK * 36];     // K  [144][32] @ stride 36
  __shared__ unsigned short Vs[32 * 160];      // V^T [32][144] @ stride 160, cols 144..159 zero
  __shared__ unsigned short Ps[3 * 16 * 168];  // per-wave P

  const int t    = threadIdx.x;
  const int wave = t / 64;
  const int lane = t & 63;
  const int ln15 = lane & 15;
  const int quad = lane >> 4;
  const int idx  = blockIdx.x;
  const int xcd  = idx & 7;
  const int j0   = idx >> 3;
  const int h    = j0 % 6;
  const int bw   = (j0 / 6) * 8 + xcd;
  const int w    = bw & 31;
  const int wh   = w * NH + h;
  const float* maskp = mask + (size_t)bw * NN;
  const unsigned short* biasp = biasb + (size_t)wh * NN;
  unsigned short* ps = &Ps[wave * 16 * 168];
  const int wv3 = wave * 3;

  // zero V pad cols 144..159
  if (t < 64) {
    u16x8 z = {0, 0, 0, 0, 0, 0, 0, 0};
    *(u16x8*)&Vs[(t >> 1) * 160 + 144 + (t & 1) * 8] = z;
  }
  // zero P pad cols 144..159 (per wave)
  {
    ushort4 z = {0, 0, 0, 0};
    *(ushort4*)&ps[(lane >> 2) * 168 + 144 + (lane & 3) * 4] = z;
  }

  // ---- phase 1: QKV GEMM for this (bw, h): 144 rows x 96 cols, K=192 ----
  f32x4 acc[3][6];
#pragma unroll
  for (int mt = 0; mt < 3; ++mt)
#pragma unroll
    for (int nt = 0; nt < 6; ++nt) acc[mt][nt] = (f32x4){0.f, 0.f, 0.f, 0.f};

#pragma unroll
  for (int kk = 0; kk < 6; ++kk) {
    const int k0 = kk * 32 + quad * 8;
    bf16x8 af[3], bfr[6];
#pragma unroll
    for (int mt = 0; mt < 3; ++mt)
      af[mt] = *(const bf16x8*)&X[(size_t)(bw * NTOK + (wv3 + mt) * 16 + ln15) * DIM + k0];
#pragma unroll
    for (int nt = 0; nt < 6; ++nt) {
      const int wrow = (nt >> 1) * DIM + h * HD + (nt & 1) * 16 + ln15;
      bfr[nt] = *(const bf16x8*)&W[(size_t)wrow * DIM + k0];
    }
#pragma unroll
    for (int mt = 0; mt < 3; ++mt)
#pragma unroll
      for (int nt = 0; nt < 6; ++nt)
        acc[mt][nt] = __builtin_amdgcn_mfma_f32_16x16x32_bf16(
            af[mt], bfr[nt], acc[mt][nt], 0, 0, 0);
  }

  // epilogue: +bias (and scale for Q), straight into LDS
#pragma unroll
  for (int nt = 0; nt < 6; ++nt) {
    const int dd   = (nt & 1) * 16 + ln15;            // 0..31 within head
    const float bias = Bv[(nt >> 1) * DIM + h * HD + dd];
#pragma unroll
    for (int mt = 0; mt < 3; ++mt) {
      const int tok = (wv3 + mt) * 16 + quad * 4;
#pragma unroll
      for (int r = 0; r < 4; ++r) {
        const float v = acc[mt][nt][r] + bias;
        if (nt < 2)      Qs[(tok + r) * 36 + dd] = f2bf(v * SCALE);
        else if (nt < 4) Ks[(tok + r) * 36 + dd] = f2bf(v);
        else             Vs[dd * 160 + tok + r]  = f2bf(v);
      }
    }
  }
  __syncthreads();

  // ---- phase 2: attention ----
  for (int g = wv3; g < wv3 + 3; ++g) {
    const int i0 = g * 16;
    const int ib = i0 + quad * 4;

    // S = Q K^T
    const bf16x8 qf = *(const bf16x8*)&Qs[(i0 + ln15) * 36 + quad * 8];
    f32x4 s[9];
#pragma unroll
    for (int jt = 0; jt < 9; ++jt) {
      const bf16x8 kf = *(const bf16x8*)&Ks[(jt * 16 + ln15) * 36 + quad * 8];
      s[jt] = (f32x4){0.f, 0.f, 0.f, 0.f};
      s[jt] = __builtin_amdgcn_mfma_f32_16x16x32_bf16(qf, kf, s[jt], 0, 0, 0);
    }

    // + bias + mask (streamed, independent loads)
#pragma unroll
    for (int jt = 0; jt < 9; ++jt) {
      const int j = jt * 16 + ln15;
#pragma unroll
      for (int r = 0; r < 4; ++r) {
        const int ij = (ib + r) * NTOK + j;
        s[jt][r] += bf2f(biasp[ij]) + maskp[ij];
      }
    }

    // softmax over j (row = ib+r lives in the 16-lane ln15 group)
    float rinv[4];
#pragma unroll
    for (int r = 0; r < 4; ++r) {
      float mx = s[0][r];
#pragma unroll
      for (int jt = 1; jt < 9; ++jt) mx = fmaxf(mx, s[jt][r]);
#pragma unroll
      for (int off = 1; off < 16; off <<= 1) mx = fmaxf(mx, __shfl_xor(mx, off));
      float sum = 0.f;
#pragma unroll
      for (int jt = 0; jt < 9; ++jt) {
        const float e = __expf(s[jt][r] - mx);
        s[jt][r] = e;
        sum += e;
      }
#pragma unroll
      for (int off = 1; off < 16; off <<= 1) sum += __shfl_xor(sum, off);
      rinv[r] = 1.0f / sum;
    }

    // P: C-layout -> LDS -> A-layout (wave-internal)
#pragma unroll
    for (int jt = 0; jt < 9; ++jt)
#pragma unroll
      for (int r = 0; r < 4; ++r)
        ps[(quad * 4 + r) * 168 + jt * 16 + ln15] = f2bf(s[jt][r]);

    // O = P V  (K padded to 160; P and V pads both zeroed)
    f32x4 o[2] = {{0.f, 0.f, 0.f, 0.f}, {0.f, 0.f, 0.f, 0.f}};
#pragma unroll
    for (int kt = 0; kt < 5; ++kt) {
      const bf16x8 pf = *(const bf16x8*)&ps[ln15 * 168 + kt * 32 + quad * 8];
#pragma unroll
      for (int nt = 0; nt < 2; ++nt) {
        const bf16x8 vf = *(const bf16x8*)&Vs[(nt * 16 + ln15) * 160 + kt * 32 + quad * 8];
        o[nt] = __builtin_amdgcn_mfma_f32_16x16x32_bf16(pf, vf, o[nt], 0, 0, 0);
      }
    }

    // store O (bf16) into [m=bw*144+i][c=h*32+d]
#pragma unroll
    for (int nt = 0; nt < 2; ++nt)
#pragma unroll
      for (int r = 0; r < 4; ++r)
        ao[(size_t)(bw * NTOK + ib + r) * DIM + h * HD + nt * 16 + ln15] =
            f2bf(o[nt][r] * rinv[r]);
  }
}

// ---------------------------------------------------------------------------
// Kernel 3: proj GEMM v6 — one block = 128 rows x ALL 192 cols.
// v4 restaged AO 3x (grid 3x540) and held 8 waves/CU. v6: N-split gone, AO
// fetched exactly once; A staged to LDS once (51.2 KB, one barrier); B-frags
// direct from global (proj_w = 73 KB, permanently L2-hot -- the pattern
// proven in fused phase 1). 512 threads / 8 waves; wave owns 16 rows x 192
// cols (acc[12], 72 MFMAs). Grid 540.
// ---------------------------------------------------------------------------
__global__ __launch_bounds__(512) void proj_gemm_k(
    const unsigned short* __restrict__ AO, const unsigned short* __restrict__ W,
    const float* __restrict__ Bv, float* __restrict__ out) {
  __shared__ unsigned short As[128 * 200];
  const int t    = threadIdx.x;
  const int wave = t >> 6;             // 0..7
  const int lane = t & 63;
  const int ln15 = lane & 15;
  const int quad = lane >> 4;
  const int m0   = blockIdx.x * 128;

  // stage A: 128 rows x 24 u16x8 (contiguous region of AO), 6 per thread
#pragma unroll
  for (int it = t; it < 3072; it += 512) {
    const int row = it / 24;
    const int c8  = (it % 24) * 8;
    *(u16x8*)&As[row * 200 + c8] = *(const u16x8*)&AO[(size_t)(m0 + row) * 192 + c8];
  }
  __syncthreads();

  f32x4 acc[12];
#pragma unroll
  for (int nt = 0; nt < 12; ++nt) acc[nt] = (f32x4){0.f, 0.f, 0.f, 0.f};

#pragma unroll
  for (int kk = 0; kk < 6; ++kk) {
    const int k0 = kk * 32 + quad * 8;
    const bf16x8 af = *(bf16x8*)&As[(wave * 16 + ln15) * 200 + k0];
    bf16x8 bfr[12];
#pragma unroll
    for (int nt = 0; nt < 12; ++nt)
      bfr[nt] = *(const bf16x8*)&W[(size_t)(nt * 16 + ln15) * DIM + k0];
#pragma unroll
    for (int nt = 0; nt < 12; ++nt)
      acc[nt] = __builtin_amdgcn_mfma_f32_16x16x32_bf16(af, bfr[nt], acc[nt], 0, 0, 0);
  }

#pragma unroll
  for (int nt = 0; nt < 12; ++nt) {
    const int colg = nt * 16 + ln15;
    const float bias = Bv[colg];
    const int mbase = m0 + wave * 16 + quad * 4;
#pragma unroll
    for (int r = 0; r < 4; ++r)
      out[(size_t)(mbase + r) * DIM + colg] = acc[nt][r] + bias;
  }
}

// ---------------------------------------------------------------------------
extern "C" void kernel_launch(void* const* d_in, const int* in_sizes, int n_in,
                              void* d_out, int out_size, void* d_ws, size_t ws_size,
                              hipStream_t stream) {
  const float* x      = (const float*)d_in[0];
  const float* mask   = (const float*)d_in[1];
  const float* qkv_w  = (const float*)d_in[2];
  const float* qkv_b  = (const float*)d_in[3];
  const float* proj_w = (const float*)d_in[4];
  const float* proj_b = (const float*)d_in[5];
  const float* btab   = (const float*)d_in[6];
  const int*   pos    = (const int*)d_in[7];
  float* out = (float*)d_out;

  unsigned short* ws = (unsigned short*)d_ws;
  const size_t sz = (size_t)MROWS * DIM;   // 13,271,040 elements
  unsigned short* aobuf = ws;
  unsigned short* biasb = ws + sz + 256;                // 192*20736 bf16 = 8 MB
  unsigned short* xbf   = biasb + (size_t)192 * NN + 256;
  unsigned short* qwbf  = xbf + sz;
  unsigned short* pwbf  = qwbf + (size_t)K3 * DIM;

  conv_bf_k<<<NX8 / 256 + NQ8 / 256 + NP8 / 256, 256, 0, stream>>>(
      x, qkv_w, proj_w, xbf, qwbf, pwbf);
  bias_pre_k<<<dim3(NW * NH, 3), 256, 0, stream>>>(btab, pos, biasb);
  fused_attn_k<<<NH * 480, 192, 0, stream>>>(
      xbf, qwbf, qkv_b, mask, biasb, aobuf);
  proj_gemm_k<<<MROWS / 128, 512, 0, stream>>>(
      aobuf, pwbf, proj_b, out);
}